// Round 4
// baseline (164.914 us; speedup 1.0000x reference)
//
#include <hip/hip_runtime.h>
#include <cmath>

typedef __attribute__((ext_vector_type(8))) short bf16x8;
typedef __attribute__((ext_vector_type(4))) float f32x4;
typedef unsigned short u16;
typedef unsigned int u32;

#define OUT1OFF 33554432   // 8*128*128*256

__device__ __forceinline__ u16 f2bf(float f) {
  union { float f; u32 u; } v; v.f = f;
  u32 r = v.u + 0x7fffu + ((v.u >> 16) & 1u);  // RNE
  return (u16)(r >> 16);
}

__device__ __forceinline__ float bf2f(u32 bits16) {
  union { u32 u; float f; } v; v.u = bits16 << 16;
  return v.f;
}

// tanh-form gelu: x * sigmoid(2c(x+0.044715x^3)), max dev from exact ~6e-4
__device__ __forceinline__ float gelu_t(float x) {
  const float x2 = x * x;
  const float z = 1.5957691216057308f * x * fmaf(0.044715f, x2, 1.0f);
  return x / (1.0f + __expf(-z));
}

// ---------------- k1: U = x@Wtop, Y = x@Wbot + b ; W1T bf16 transpose ----------------
__global__ __launch_bounds__(256) void k1_prep(
    const float* __restrict__ x, const float* __restrict__ Wn2e,
    const float* __restrict__ bn2e, const float* __restrict__ W1,
    float* __restrict__ Uw, float* __restrict__ Yw, u16* __restrict__ W1T)
{
  __shared__ float xl[4][256];
  const int t = threadIdx.x;
  const int blk = blockIdx.x;      // 0..255, 4 node-rows each
  const int r0 = blk * 4;
  {
    const int rr = t >> 6, c4 = (t & 63) * 4;
    *(float4*)&xl[rr][c4] = *(const float4*)&x[(r0 + rr) * 256 + c4];
  }
  __syncthreads();
  const int c = t;
  float u0=0.f,u1=0.f,u2=0.f,u3=0.f,y0=0.f,y1=0.f,y2=0.f,y3=0.f;
  #pragma unroll 4
  for (int k = 0; k < 256; ++k) {
    const float wt = Wn2e[k * 256 + c];
    const float wb = Wn2e[(k + 256) * 256 + c];
    const float a0 = xl[0][k], a1 = xl[1][k], a2 = xl[2][k], a3 = xl[3][k];
    u0 = fmaf(a0, wt, u0); u1 = fmaf(a1, wt, u1);
    u2 = fmaf(a2, wt, u2); u3 = fmaf(a3, wt, u3);
    y0 = fmaf(a0, wb, y0); y1 = fmaf(a1, wb, y1);
    y2 = fmaf(a2, wb, y2); y3 = fmaf(a3, wb, y3);
  }
  const float bb = bn2e[c];
  Uw[(r0+0)*256+c]=u0; Uw[(r0+1)*256+c]=u1; Uw[(r0+2)*256+c]=u2; Uw[(r0+3)*256+c]=u3;
  Yw[(r0+0)*256+c]=y0+bb; Yw[(r0+1)*256+c]=y1+bb; Yw[(r0+2)*256+c]=y2+bb; Yw[(r0+3)*256+c]=y3+bb;
  if (blk < 128) W1T[blk * 256 + t] = f2bf(W1[t * 128 + blk]);
}

// ---- k2: barrier-free fused. Each WAVE owns 16 j-rows of one (b,i) end-to-end. ----
// A-frags (ez, bf16) built in registers; B-frags (W1T) from global (L2-resident);
// GEMM3 reduced in-wave via shfl butterfly; epilogue streamed from same regs.
__global__ __launch_bounds__(256, 4) void k2_fused(
    const float* __restrict__ Uw, const float* __restrict__ Yw,
    const u16* __restrict__ W1T, const float* __restrict__ b1,
    const float* __restrict__ W2, const float* __restrict__ b2p,
    const float* __restrict__ E, float* __restrict__ out)
{
  const int t = threadIdx.x;
  const int l = t & 63;
  const int gw = blockIdx.x * 4 + (t >> 6);   // global wave id, 0..8191
  const int pair = gw >> 3;                   // b*128 + i
  const int wseg = gw & 7;                    // which 16-row j segment
  const int b = pair >> 7;
  const int l15 = l & 15, lh = l >> 4;
  const int jrow = wseg * 16 + l15;           // this lane's row (A & epilogue)
  const int kbase = lh * 8;

  const float* __restrict__ Urow = Uw + pair * 256;
  const float* __restrict__ Yrow = Yw + (b * 128 + jrow) * 256;

  // Phase 1: ez = gelu(U+Y) directly into MFMA A-fragment layout (bf16, regs)
  bf16x8 ezf[8];
  #pragma unroll
  for (int ks = 0; ks < 8; ++ks) {
    const int k = ks * 32 + kbase;
    const float4 ua = *(const float4*)&Urow[k];
    const float4 ub = *(const float4*)&Urow[k + 4];
    const float4 ya = *(const float4*)&Yrow[k];
    const float4 yb = *(const float4*)&Yrow[k + 4];
    bf16x8 e;
    e[0] = (short)f2bf(gelu_t(ua.x + ya.x));
    e[1] = (short)f2bf(gelu_t(ua.y + ya.y));
    e[2] = (short)f2bf(gelu_t(ua.z + ya.z));
    e[3] = (short)f2bf(gelu_t(ua.w + ya.w));
    e[4] = (short)f2bf(gelu_t(ub.x + yb.x));
    e[5] = (short)f2bf(gelu_t(ub.y + yb.y));
    e[6] = (short)f2bf(gelu_t(ub.z + yb.z));
    e[7] = (short)f2bf(gelu_t(ub.w + yb.w));
    ezf[ks] = e;
  }

  // Phase 2: h = ez @ W1 over all N=128 (8 n-tiles), B-frags from global
  f32x4 acc[8];
  #pragma unroll
  for (int nt = 0; nt < 8; ++nt) acc[nt] = (f32x4){0.f,0.f,0.f,0.f};
  #pragma unroll
  for (int ks = 0; ks < 8; ++ks) {
    const bf16x8 a = ezf[ks];
    const int k = ks * 32 + kbase;
    #pragma unroll
    for (int nt = 0; nt < 8; ++nt) {
      const bf16x8 bv = *(const bf16x8*)&W1T[(nt * 16 + l15) * 256 + k];
      acc[nt] = __builtin_amdgcn_mfma_f32_16x16x32_bf16(a, bv, acc[nt], 0, 0, 0);
    }
  }

  // Phase 3: GEMM3 in-wave: e2v_pre[row=lh*4+r] = sum_col relu(h+b1)*W2
  float ps0=0.f, ps1=0.f, ps2=0.f, ps3=0.f;
  #pragma unroll
  for (int nt = 0; nt < 8; ++nt) {
    const int col = nt * 16 + l15;
    const float bv = b1[col], wv = W2[col];
    ps0 += fmaxf(acc[nt][0] + bv, 0.f) * wv;
    ps1 += fmaxf(acc[nt][1] + bv, 0.f) * wv;
    ps2 += fmaxf(acc[nt][2] + bv, 0.f) * wv;
    ps3 += fmaxf(acc[nt][3] + bv, 0.f) * wv;
  }
  #pragma unroll
  for (int m = 1; m < 16; m <<= 1) {
    ps0 += __shfl_xor(ps0, m, 64);
    ps1 += __shfl_xor(ps1, m, 64);
    ps2 += __shfl_xor(ps2, m, 64);
    ps3 += __shfl_xor(ps3, m, 64);
  }
  const float b2 = b2p[0];
  const float e0 = fmaxf(ps0 + b2, 0.f);
  const float e1 = fmaxf(ps1 + b2, 0.f);
  const float e2 = fmaxf(ps2 + b2, 0.f);
  const float e3 = fmaxf(ps3 + b2, 0.f);
  // redistribute: lane needs e2v of row l15 (held as reg (l15&3) of lanes lh=l15>>2)
  const int srcLane = ((l15 >> 2) << 4) | l15;
  const float s0 = __shfl(e0, srcLane, 64);
  const float s1 = __shfl(e1, srcLane, 64);
  const float s2 = __shfl(e2, srcLane, 64);
  const float s3 = __shfl(e3, srcLane, 64);
  const float t01 = (l15 & 1) ? s1 : s0;
  const float t23 = (l15 & 1) ? s3 : s2;
  const float s = (l15 & 2) ? t23 : t01;     // e2v[jrow]
  if (l < 16) out[OUT1OFF + pair * 128 + wseg * 16 + l] = s;
  float kk = 2.f;
  if (s >= 0.2f && s < 1.0f) kk -= 2.f * sqrtf(s * 1e-9f);

  // Phase 4: epilogue for this lane's row: out0 = ez + 0.5*(k - exp(sigmoid(ez)))*E
  const int eBase = pair * 32768 + jrow * 256;
  #pragma unroll
  for (int ks = 0; ks < 8; ++ks) {
    const int k = ks * 32 + kbase;
    const float4 va = *(const float4*)&E[eBase + k];
    const float4 vb = *(const float4*)&E[eBase + k + 4];
    const bf16x8 e = ezf[ks];
    float4 oa, ob;
    {
      const float ez = bf2f((u16)e[0]);
      oa.x = ez + 0.5f * (kk - __expf(1.f / (1.f + __expf(-ez)))) * va.x;
    }
    {
      const float ez = bf2f((u16)e[1]);
      oa.y = ez + 0.5f * (kk - __expf(1.f / (1.f + __expf(-ez)))) * va.y;
    }
    {
      const float ez = bf2f((u16)e[2]);
      oa.z = ez + 0.5f * (kk - __expf(1.f / (1.f + __expf(-ez)))) * va.z;
    }
    {
      const float ez = bf2f((u16)e[3]);
      oa.w = ez + 0.5f * (kk - __expf(1.f / (1.f + __expf(-ez)))) * va.w;
    }
    {
      const float ez = bf2f((u16)e[4]);
      ob.x = ez + 0.5f * (kk - __expf(1.f / (1.f + __expf(-ez)))) * vb.x;
    }
    {
      const float ez = bf2f((u16)e[5]);
      ob.y = ez + 0.5f * (kk - __expf(1.f / (1.f + __expf(-ez)))) * vb.y;
    }
    {
      const float ez = bf2f((u16)e[6]);
      ob.z = ez + 0.5f * (kk - __expf(1.f / (1.f + __expf(-ez)))) * vb.z;
    }
    {
      const float ez = bf2f((u16)e[7]);
      ob.w = ez + 0.5f * (kk - __expf(1.f / (1.f + __expf(-ez)))) * vb.w;
    }
    *(float4*)&out[eBase + k] = oa;
    *(float4*)&out[eBase + k + 4] = ob;
  }
}

extern "C" void kernel_launch(void* const* d_in, const int* in_sizes, int n_in,
                              void* d_out, int out_size, void* d_ws, size_t ws_size,
                              hipStream_t stream) {
  const float* x    = (const float*)d_in[0];   // [1024, 256]
  const float* E    = (const float*)d_in[1];   // [131072, 256]
  const float* Wn2e = (const float*)d_in[2];   // [512, 256]
  const float* bn2e = (const float*)d_in[3];   // [256]
  const float* W1   = (const float*)d_in[4];   // [256, 128]
  const float* b1   = (const float*)d_in[5];   // [128]
  const float* W2   = (const float*)d_in[6];   // [128]
  const float* b2   = (const float*)d_in[7];   // [1]
  float* out = (float*)d_out;

  float* Uw = (float*)d_ws;                    // [1024, 256] f32
  float* Yw = Uw + 262144;                     // [1024, 256] f32
  u16*  W1T = (u16*)(Yw + 262144);             // [128, 256] bf16

  hipLaunchKernelGGL(k1_prep, dim3(256), dim3(256), 0, stream,
                     x, Wn2e, bn2e, W1, Uw, Yw, W1T);
  // 8192 waves = 1024 pairs x 8 segments; 4 waves/block
  hipLaunchKernelGGL(k2_fused, dim3(2048), dim3(256), 0, stream,
                     Uw, Yw, W1T, b1, W2, b2, E, out);
}

// Round 5
// 157.866 us; speedup vs baseline: 1.0446x; 1.0446x over previous
//
#include <hip/hip_runtime.h>
#include <cmath>

typedef __attribute__((ext_vector_type(8))) short bf16x8;
typedef __attribute__((ext_vector_type(4))) float f32x4;
typedef unsigned short u16;
typedef unsigned int u32;

#define OUT1OFF 33554432   // 8*128*128*256

__device__ __forceinline__ u16 f2bf(float f) {
  union { float f; u32 u; } v; v.f = f;
  u32 r = v.u + 0x7fffu + ((v.u >> 16) & 1u);  // RNE
  return (u16)(r >> 16);
}

// tanh-form gelu: x * sigmoid(2c(x+0.044715x^3)), max dev from exact ~6e-4
__device__ __forceinline__ float gelu_t(float x) {
  const float x2 = x * x;
  const float z = 1.5957691216057308f * x * fmaf(0.044715f, x2, 1.0f);
  return x / (1.0f + __expf(-z));
}

// ---------------- k1: U = x@Wtop, Y = x@Wbot + b ; W1T bf16 transpose ----------------
__global__ __launch_bounds__(256) void k1_prep(
    const float* __restrict__ x, const float* __restrict__ Wn2e,
    const float* __restrict__ bn2e, const float* __restrict__ W1,
    float* __restrict__ Uw, float* __restrict__ Yw, u16* __restrict__ W1T)
{
  __shared__ float xl[4][256];
  const int t = threadIdx.x;
  const int blk = blockIdx.x;      // 0..255, 4 node-rows each
  const int r0 = blk * 4;
  {
    const int rr = t >> 6, c4 = (t & 63) * 4;
    *(float4*)&xl[rr][c4] = *(const float4*)&x[(r0 + rr) * 256 + c4];
  }
  __syncthreads();
  const int c = t;
  float u0=0.f,u1=0.f,u2=0.f,u3=0.f,y0=0.f,y1=0.f,y2=0.f,y3=0.f;
  #pragma unroll 4
  for (int k = 0; k < 256; ++k) {
    const float wt = Wn2e[k * 256 + c];
    const float wb = Wn2e[(k + 256) * 256 + c];
    const float a0 = xl[0][k], a1 = xl[1][k], a2 = xl[2][k], a3 = xl[3][k];
    u0 = fmaf(a0, wt, u0); u1 = fmaf(a1, wt, u1);
    u2 = fmaf(a2, wt, u2); u3 = fmaf(a3, wt, u3);
    y0 = fmaf(a0, wb, y0); y1 = fmaf(a1, wb, y1);
    y2 = fmaf(a2, wb, y2); y3 = fmaf(a3, wb, y3);
  }
  const float bb = bn2e[c];
  Uw[(r0+0)*256+c]=u0; Uw[(r0+1)*256+c]=u1; Uw[(r0+2)*256+c]=u2; Uw[(r0+3)*256+c]=u3;
  Yw[(r0+0)*256+c]=y0+bb; Yw[(r0+1)*256+c]=y1+bb; Yw[(r0+2)*256+c]=y2+bb; Yw[(r0+3)*256+c]=y3+bb;
  if (blk < 128) W1T[blk * 256 + t] = f2bf(W1[t * 128 + blk]);
}

// ---- k2: e2v only. Each WAVE owns 16 j-rows of one (b,i); barrier-free, no LDS. ----
// ez A-frag built per k-slice (4 live regs), consumed immediately by MFMA;
// B-frags from global W1T (L1/L2-resident); GEMM3 via in-wave shfl butterfly.
__global__ __launch_bounds__(256) void k2_e2v(
    const float* __restrict__ Uw, const float* __restrict__ Yw,
    const u16* __restrict__ W1T, const float* __restrict__ b1,
    const float* __restrict__ W2, const float* __restrict__ b2p,
    float* __restrict__ out1)
{
  const int t = threadIdx.x;
  const int l = t & 63;
  const int gw = blockIdx.x * 4 + (t >> 6);   // global wave id, 0..8191
  const int pair = gw >> 3;                   // b*128 + i
  const int wseg = gw & 7;                    // 16-row j segment
  const int b = pair >> 7;
  const int l15 = l & 15, lh = l >> 4;
  const int jrow = wseg * 16 + l15;
  const int kbase = lh * 8;

  const float* __restrict__ Urow = Uw + pair * 256;
  const float* __restrict__ Yrow = Yw + (b * 128 + jrow) * 256;

  f32x4 acc[8];
  #pragma unroll
  for (int nt = 0; nt < 8; ++nt) acc[nt] = (f32x4){0.f,0.f,0.f,0.f};
  #pragma unroll
  for (int ks = 0; ks < 8; ++ks) {
    const int k = ks * 32 + kbase;
    const float4 ua = *(const float4*)&Urow[k];
    const float4 ub = *(const float4*)&Urow[k + 4];
    const float4 ya = *(const float4*)&Yrow[k];
    const float4 yb = *(const float4*)&Yrow[k + 4];
    bf16x8 e;
    e[0] = (short)f2bf(gelu_t(ua.x + ya.x));
    e[1] = (short)f2bf(gelu_t(ua.y + ya.y));
    e[2] = (short)f2bf(gelu_t(ua.z + ya.z));
    e[3] = (short)f2bf(gelu_t(ua.w + ya.w));
    e[4] = (short)f2bf(gelu_t(ub.x + yb.x));
    e[5] = (short)f2bf(gelu_t(ub.y + yb.y));
    e[6] = (short)f2bf(gelu_t(ub.z + yb.z));
    e[7] = (short)f2bf(gelu_t(ub.w + yb.w));
    #pragma unroll
    for (int nt = 0; nt < 8; ++nt) {
      const bf16x8 bv = *(const bf16x8*)&W1T[(nt * 16 + l15) * 256 + k];
      acc[nt] = __builtin_amdgcn_mfma_f32_16x16x32_bf16(e, bv, acc[nt], 0, 0, 0);
    }
  }

  // GEMM3 in-wave: e2v_pre[row=lh*4+r] = sum_col relu(h+b1)*W2
  float ps0=0.f, ps1=0.f, ps2=0.f, ps3=0.f;
  #pragma unroll
  for (int nt = 0; nt < 8; ++nt) {
    const int col = nt * 16 + l15;
    const float bv = b1[col], wv = W2[col];
    ps0 += fmaxf(acc[nt][0] + bv, 0.f) * wv;
    ps1 += fmaxf(acc[nt][1] + bv, 0.f) * wv;
    ps2 += fmaxf(acc[nt][2] + bv, 0.f) * wv;
    ps3 += fmaxf(acc[nt][3] + bv, 0.f) * wv;
  }
  #pragma unroll
  for (int m = 1; m < 16; m <<= 1) {
    ps0 += __shfl_xor(ps0, m, 64);
    ps1 += __shfl_xor(ps1, m, 64);
    ps2 += __shfl_xor(ps2, m, 64);
    ps3 += __shfl_xor(ps3, m, 64);
  }
  const float b2 = b2p[0];
  const float e0 = fmaxf(ps0 + b2, 0.f);
  const float e1 = fmaxf(ps1 + b2, 0.f);
  const float e2 = fmaxf(ps2 + b2, 0.f);
  const float e3 = fmaxf(ps3 + b2, 0.f);
  // lane l<16 needs e2v of row l (held as reg (l&3) of lanes lh=l>>2)
  const int srcLane = ((l15 >> 2) << 4) | l15;
  const float s0 = __shfl(e0, srcLane, 64);
  const float s1 = __shfl(e1, srcLane, 64);
  const float s2 = __shfl(e2, srcLane, 64);
  const float s3 = __shfl(e3, srcLane, 64);
  const float t01 = (l15 & 1) ? s1 : s0;
  const float t23 = (l15 & 1) ? s3 : s2;
  const float s = (l15 & 2) ? t23 : t01;     // e2v[jrow]
  if (l < 16) out1[pair * 128 + wseg * 16 + l] = s;
}

// ---------------- k3: streaming epilogue (BW-bound), cheap gelu ----------------
__global__ __launch_bounds__(256) void k3_epi(
    const float* __restrict__ Uw, const float* __restrict__ Yw,
    const float* __restrict__ E, const float* __restrict__ e2vp,
    float* __restrict__ out0)
{
  const int t = threadIdx.x;
  const int base = blockIdx.x * 4096;
  #pragma unroll 2
  for (int it = 0; it < 16; ++it) {
    const int gid = base + it * 256 + t;      // float4 index, < 2^23
    const int g = gid >> 6;                   // edge index (wave-uniform)
    const int c0 = (gid & 63) * 4;
    const int ui = g >> 7;                    // b*128 + i
    const int yi = ((g >> 14) << 7) | (g & 127);  // b*128 + j
    const float e2v = e2vp[g];
    float hk = 1.f;                           // 0.5*k
    if (e2v >= 0.2f && e2v < 1.0f) hk -= sqrtf(e2v * 1e-9f);
    const float4 uv = *(const float4*)&Uw[ui * 256 + c0];
    const float4 yv = *(const float4*)&Yw[yi * 256 + c0];
    const float4 ev = *(const float4*)&E[gid * 4];
    float4 o;
    {
      const float ez = gelu_t(uv.x + yv.x);
      const float sg = 1.f / (1.f + __expf(-ez));
      o.x = ez + (hk - 0.5f * __expf(sg)) * ev.x;
    }
    {
      const float ez = gelu_t(uv.y + yv.y);
      const float sg = 1.f / (1.f + __expf(-ez));
      o.y = ez + (hk - 0.5f * __expf(sg)) * ev.y;
    }
    {
      const float ez = gelu_t(uv.z + yv.z);
      const float sg = 1.f / (1.f + __expf(-ez));
      o.z = ez + (hk - 0.5f * __expf(sg)) * ev.z;
    }
    {
      const float ez = gelu_t(uv.w + yv.w);
      const float sg = 1.f / (1.f + __expf(-ez));
      o.w = ez + (hk - 0.5f * __expf(sg)) * ev.w;
    }
    *(float4*)&out0[gid * 4] = o;
  }
}

extern "C" void kernel_launch(void* const* d_in, const int* in_sizes, int n_in,
                              void* d_out, int out_size, void* d_ws, size_t ws_size,
                              hipStream_t stream) {
  const float* x    = (const float*)d_in[0];   // [1024, 256]
  const float* E    = (const float*)d_in[1];   // [131072, 256]
  const float* Wn2e = (const float*)d_in[2];   // [512, 256]
  const float* bn2e = (const float*)d_in[3];   // [256]
  const float* W1   = (const float*)d_in[4];   // [256, 128]
  const float* b1   = (const float*)d_in[5];   // [128]
  const float* W2   = (const float*)d_in[6];   // [128]
  const float* b2   = (const float*)d_in[7];   // [1]
  float* out = (float*)d_out;

  float* Uw = (float*)d_ws;                    // [1024, 256] f32
  float* Yw = Uw + 262144;                     // [1024, 256] f32
  u16*  W1T = (u16*)(Yw + 262144);             // [128, 256] bf16

  hipLaunchKernelGGL(k1_prep, dim3(256), dim3(256), 0, stream,
                     x, Wn2e, bn2e, W1, Uw, Yw, W1T);
  hipLaunchKernelGGL(k2_e2v, dim3(2048), dim3(256), 0, stream,
                     Uw, Yw, W1T, b1, W2, b2, out + OUT1OFF);
  hipLaunchKernelGGL(k3_epi, dim3(2048), dim3(256), 0, stream,
                     Uw, Yw, E, out + OUT1OFF, out);
}